// Round 18
// baseline (872.847 us; speedup 1.0000x reference)
//
#include <hip/hip_runtime.h>

#define NF    50000
#define PADP  50001
#define KN    9
#define KTOT  2304
#define NCHUNK 782
#define BM4   256
#define NBLK4 196        // 196*256 = 50176 >= 50000; grid <= 256 -> makespan = 1 block
#define NKT   36

// ---- ws layout (bytes) ----
#define WT_OFF   0u
#define FLAG_OFF 1179648u
#define CNT_OFF  1179904u
#define PADX_OFF 1183744u

typedef float f32x16 __attribute__((ext_vector_type(16)));
typedef __bf16 bf16x8 __attribute__((ext_vector_type(8)));

typedef const __attribute__((address_space(1))) unsigned int* gas_t;
typedef __attribute__((address_space(3))) unsigned int* las_t;

static __device__ __forceinline__ void gll16(const void* g, void* l) {
  __builtin_amdgcn_global_load_lds((gas_t)g, (las_t)l, 16, 0, 0);
}

static __device__ __forceinline__ unsigned short f2bf(float f) {
  unsigned int u = __builtin_bit_cast(unsigned int, f);
  u = u + 0x7fffu + ((u >> 16) & 1u);      // RNE
  return (unsigned short)(u >> 16);
}

// ---------- preprocessing (unchanged) ----------

__global__ void k_prep(const float* __restrict__ w, unsigned short* __restrict__ wt,
                       const unsigned char* __restrict__ pad, int* __restrict__ cnt,
                       const unsigned int* __restrict__ raw, int* __restrict__ flag) {
  if (blockIdx.x < 256) {
    int o = blockIdx.x;
    int i = threadIdx.x;
    const float* wr = w + (o * 256 + i) * 9;
    float wv[9];
    float s = 0.f;
#pragma unroll
    for (int k = 0; k < 9; ++k) { wv[k] = wr[k]; s += wv[k] * wv[k]; }
#pragma unroll
    for (int d = 32; d >= 1; d >>= 1) s += __shfl_xor(s, d);
    __shared__ float red[4];
    if ((i & 63) == 0) red[i >> 6] = s;
    __syncthreads();
    float dc = rsqrtf(red[0] + red[1] + red[2] + red[3] + 1e-8f);
#pragma unroll
    for (int k = 0; k < 9; ++k)
      wt[o * KTOT + k * 256 + i] = f2bf(wv[k] * dc);
  } else {
    int cb = blockIdx.x - 256;
    int t = cb * 256 + threadIdx.x;
    bool ip = (t < PADP) ? (pad[t] != 0) : true;
    unsigned long long m = __ballot(ip);
    int c = t >> 6;
    if ((threadIdx.x & 63) == 0 && c < NCHUNK) cnt[c] = __popcll(m);
    if (cb == 0 && threadIdx.x < 64) {
      unsigned int v = raw[threadIdx.x * 2 + 1];
      unsigned long long nz = __ballot(v != 0u);
      if (threadIdx.x == 0) flag[0] = (nz == 0ull) ? 1 : 0;
    }
  }
}

__global__ __launch_bounds__(256) void k_rankpadx(
    const float* __restrict__ x, const unsigned char* __restrict__ pad,
    const int* __restrict__ cnt, unsigned short* __restrict__ padx) {
  const int c = blockIdx.x;
  const int tid = threadIdx.x, w = tid >> 6, lane = tid & 63;
  int s = 0;
  for (int i = tid; i < c; i += 256) s += cnt[i];
#pragma unroll
  for (int d = 32; d >= 1; d >>= 1) s += __shfl_xor(s, d);
  __shared__ int red[4];
  __shared__ int rnk[64];
  if (lane == 0) red[w] = s;
  __syncthreads();
  const int S = red[0] + red[1] + red[2] + red[3];
  if (w == 0) {
    int p = c * 64 + lane;
    bool ip = (p < PADP) ? (pad[p] != 0) : true;
    unsigned long long m = __ballot(ip);
    int before = __popcll(m & ((1ull << lane) - 1ull));
    rnk[lane] = ip ? -1 : (p - (S + before));
  }
  __syncthreads();
  const int col = lane * 4;
#pragma unroll
  for (int i = 0; i < 16; ++i) {
    int rl = i * 4 + w;
    int pp = c * 64 + rl;
    if (pp >= PADP) continue;
    int rr = rnk[rl];
    ushort4 ov;
    if (rr < 0) { ov.x = 0; ov.y = 0; ov.z = 0; ov.w = 0; }
    else {
      const float4 v = *(const float4*)(x + rr * 256 + col);
      ov.x = f2bf(v.x); ov.y = f2bf(v.y); ov.z = f2bf(v.z); ov.w = f2bf(v.w);
    }
    *(ushort4*)(padx + pp * 256 + col) = ov;
  }
}

// ---------- main gathered GEMM: 32x32x16 MFMA, K-major LDS, 16 waves ----------
// BM=256 x BN=256 x BK=64, 1024 thr (16 waves 4M x 4N), wave-tile 64x64
// (2x2 frags of 32x32x16; acc 4 x f32x16 = 64 VGPR -> 4 waves/SIMD).
// LDS 160KiB exact: A ring-3 x 32KB @0/32K/64K + B dbuf 2 x 32KB @96K/128K.
// K-MAJOR layout [kblk 0..7][row 0..255] x 16B: fragment reads are fully
// contiguous (lanes 0-31 -> 512B linear) -> ZERO bank conflicts, no swizzle.
// Staging: unit (wave,instr j) -> (kblk = (2wv+j)&7, rowgroup = wv>>2);
// dest = buf + kblk*4096 + rg*1024 (+lane*16 by HW); per-lane gathered source.
// idx: 9 named registers per thread (its single staged row), loaded once.
// Per K-tile: vmcnt(2) + ONE barrier; stage B(kt+1)(2), A(kt+2)(2);
// 4 ks-steps of [4 ds_read_b128 + 4 MFMA]. Reads/K-tile 256 (was 288 with
// 1.29x less bytes/FLOP) -> LDS-read time ~3084cy vs MFMA 2066cy.
__global__ __launch_bounds__(1024, 1) void k_main(
    const unsigned short* __restrict__ padx,   // [50001][256] bf16
    const unsigned short* __restrict__ wt,     // [256][2304] bf16
    const void* __restrict__ nbr,              // [50000][9] int64 or int32
    const int* __restrict__ flag,
    const float* __restrict__ bias,            // [256]
    float* __restrict__ out) {                 // [50000][256] f32
  __shared__ __align__(16) unsigned char sm[163840];
  const int tid = threadIdx.x;
  const int wv = tid >> 6, lane = tid & 63;
  const int l5 = lane & 31, hb = lane >> 5;
  const int m0 = blockIdx.x * BM4;
  const int wm = wv >> 2, wn = wv & 3;
  const int rg = wv >> 2;                     // staging row/col group
  const int kb0 = (wv * 2) & 7, kb1 = kb0 + 1;

  // bias (vmem; drained by first vmcnt via in-order retirement)
  float bv0 = bias[wn * 64 + 0  + l5];
  float bv1 = bias[wn * 64 + 32 + l5];

  // per-thread staged row + its 9 gather indices (named regs, loaded once)
  int face = m0 + rg * 64 + lane;
  if (face > NF - 1) face = NF - 1;
  const bool f64 = (flag[0] != 0);
  const long long* n64 = (const long long*)nbr;
  const int* n32 = (const int*)nbr;
#define LDI(G) (f64 ? (int)n64[face * 9 + (G)] : n32[face * 9 + (G)])
  const int p0 = LDI(0), p1 = LDI(1), p2 = LDI(2), p3 = LDI(3), p4 = LDI(4),
            p5 = LDI(5), p6 = LDI(6), p7 = LDI(7), p8 = LDI(8);
#undef LDI

  const char* pxb = (const char*)padx;
  const char* wtc0 = (const char*)wt + (long)(rg * 64 + lane) * 4608 + kb0 * 16;
  const char* wtc1 = wtc0 + 16;
  const int adst0 = kb0 * 4096 + rg * 1024;
  const int adst1 = adst0 + 4096;

  // fragment read lane offsets (K-major: kb*4096 + row*16)
  const int laneA0 = hb * 4096 + (wm * 64 + l5) * 16;
  const int laneA1 = laneA0 + 512;
  const int laneB0 = hb * 4096 + (wn * 64 + l5) * 16;
  const int laneB1 = laneB0 + 512;

  f32x16 acc00 = {0.f}, acc01 = {0.f}, acc10 = {0.f}, acc11 = {0.f};

  // ---- prologue stages (queue: A0 x2, B0 x2, A1 x2) ----
  gll16(pxb + ((long)p0 << 9) + kb0 * 16, sm + adst0);
  gll16(pxb + ((long)p0 << 9) + kb1 * 16, sm + adst1);
  gll16(wtc0, sm + 98304 + adst0);
  gll16(wtc1 - 16 + kb1 * 16 - kb0 * 16 + 16 - 16, sm + 98304 + adst1);  // = wtc1
  gll16(pxb + ((long)p0 << 9) + 128 + kb0 * 16, sm + 32768 + adst0);
  gll16(pxb + ((long)p0 << 9) + 128 + kb1 * 16, sm + 32768 + adst1);

#define LD(p) (*(const bf16x8*)(p))
#define SB __builtin_amdgcn_sched_barrier(0);
#define KS(ks, aC_, bC_) { \
  bf16x8 a0 = LD(sm + (aC_) + (ks) * 8192 + laneA0); \
  bf16x8 a1 = LD(sm + (aC_) + (ks) * 8192 + laneA1); \
  bf16x8 b0 = LD(sm + (bC_) + (ks) * 8192 + laneB0); \
  bf16x8 b1 = LD(sm + (bC_) + (ks) * 8192 + laneB1); \
  __builtin_amdgcn_s_setprio(1); \
  acc00 = __builtin_amdgcn_mfma_f32_32x32x16_bf16(a0, b0, acc00, 0, 0, 0); \
  acc01 = __builtin_amdgcn_mfma_f32_32x32x16_bf16(a0, b1, acc01, 0, 0, 0); \
  acc10 = __builtin_amdgcn_mfma_f32_32x32x16_bf16(a1, b0, acc10, 0, 0, 0); \
  acc11 = __builtin_amdgcn_mfma_f32_32x32x16_bf16(a1, b1, acc11, 0, 0, 0); \
  __builtin_amdgcn_s_setprio(0); \
}
#define KTILE(kt, PC, PN) { \
  asm volatile("s_waitcnt vmcnt(2)" ::: "memory"); \
  SB __builtin_amdgcn_s_barrier(); SB \
  { const int kbyB = (((kt) + 1 < NKT) ? (kt) + 1 : NKT - 1) * 128; \
    const int bO_ = 98304 + ((((kt) + 1) & 1) << 15); \
    gll16(wtc0 + kbyB, sm + bO_ + adst0); \
    gll16(wtc1 + kbyB, sm + bO_ + adst1); } \
  { const int c0b = (((kt) + 2) & 3) * 128; \
    const int p_ = ((((kt)) & 3) < 2) ? (PC) : (PN); \
    const int aS_ = (((kt) + 2) % 3) * 32768; \
    const char* asrc = pxb + ((long)p_ << 9) + c0b; \
    gll16(asrc + kb0 * 16, sm + aS_ + adst0); \
    gll16(asrc + kb1 * 16, sm + aS_ + adst1); } \
  SB \
  { const int aC_ = ((kt) % 3) * 32768; \
    const int bC_ = 98304 + (((kt) & 1) << 15); \
    KS(0, aC_, bC_) KS(1, aC_, bC_) KS(2, aC_, bC_) KS(3, aC_, bC_) } \
}

  KTILE(0,p0,p1)  KTILE(1,p0,p1)  KTILE(2,p0,p1)  KTILE(3,p0,p1)
  KTILE(4,p1,p2)  KTILE(5,p1,p2)  KTILE(6,p1,p2)  KTILE(7,p1,p2)
  KTILE(8,p2,p3)  KTILE(9,p2,p3)  KTILE(10,p2,p3) KTILE(11,p2,p3)
  KTILE(12,p3,p4) KTILE(13,p3,p4) KTILE(14,p3,p4) KTILE(15,p3,p4)
  KTILE(16,p4,p5) KTILE(17,p4,p5) KTILE(18,p4,p5) KTILE(19,p4,p5)
  KTILE(20,p5,p6) KTILE(21,p5,p6) KTILE(22,p5,p6) KTILE(23,p5,p6)
  KTILE(24,p6,p7) KTILE(25,p6,p7) KTILE(26,p6,p7) KTILE(27,p6,p7)
  KTILE(28,p7,p8) KTILE(29,p7,p8) KTILE(30,p7,p8) KTILE(31,p7,p8)
  KTILE(32,p8,p8) KTILE(33,p8,p8) KTILE(34,p8,p8) KTILE(35,p8,p8)
#undef KTILE
#undef KS
#undef LD
#undef SB
  asm volatile("s_waitcnt vmcnt(0)" ::: "memory");

  // ---- epilogue: bias + store ----
  // 32x32 C/D: col = lane&31, row = (r&3) + 8*(r>>2) + 4*hb  [m74/m101]
#define STORE(ACC, MI, NI, BV) { \
    const int col = wn * 64 + (NI) * 32 + l5; \
    _Pragma("unroll") \
    for (int r = 0; r < 16; ++r) { \
      const int row = m0 + wm * 64 + (MI) * 32 + (r & 3) + 8 * (r >> 2) + 4 * hb; \
      if (row < NF) out[row * 256 + col] = ACC[r] + (BV); \
    } }
  STORE(acc00, 0, 0, bv0)
  STORE(acc01, 0, 1, bv1)
  STORE(acc10, 1, 0, bv0)
  STORE(acc11, 1, 1, bv1)
#undef STORE
}

extern "C" void kernel_launch(void* const* d_in, const int* in_sizes, int n_in,
                              void* d_out, int out_size, void* d_ws, size_t ws_size,
                              hipStream_t stream) {
  const float* x = (const float*)d_in[0];
  const float* wfull = (const float*)d_in[1];
  const float* bias = (const float*)d_in[2];
  const void* nbr = d_in[3];
  const unsigned char* pad = (const unsigned char*)d_in[4];
  float* out = (float*)d_out;
  char* ws = (char*)d_ws;

  unsigned short* wt   = (unsigned short*)(ws + WT_OFF);
  int* flag            = (int*)(ws + FLAG_OFF);
  int* cnt             = (int*)(ws + CNT_OFF);
  unsigned short* padx = (unsigned short*)(ws + PADX_OFF);

  k_prep<<<452, 256, 0, stream>>>(wfull, wt, pad, cnt, (const unsigned int*)nbr, flag);
  k_rankpadx<<<NCHUNK, 256, 0, stream>>>(x, pad, cnt, padx);
  k_main<<<NBLK4, 1024, 0, stream>>>(padx, wt, nbr, flag, bias, out);
}

// Round 19
// 112.635 us; speedup vs baseline: 7.7494x; 7.7494x over previous
//
#include <hip/hip_runtime.h>

#define NF    50000
#define PADP  50001
#define KN    9
#define KTOT  2304
#define NCHUNK 782
#define BM4   256
#define NBLK4 196        // 196*256 = 50176 >= 50000; grid <= 256 CUs
#define NKT   36         // 2304/64 K-tiles
#define BB    98304      // B dbuf base (2 x 32768); A ring-3 at 0/32768/65536

// ---- ws layout (bytes) ----
#define WT_OFF   0u
#define FLAG_OFF 1179648u
#define CNT_OFF  1179904u
#define PADX_OFF 1183744u

typedef float f32x4 __attribute__((ext_vector_type(4)));
typedef __bf16 bf16x8 __attribute__((ext_vector_type(8)));

typedef const __attribute__((address_space(1))) unsigned int* gas_t;
typedef __attribute__((address_space(3))) unsigned int* las_t;

static __device__ __forceinline__ void gll16(const void* g, void* l) {
  __builtin_amdgcn_global_load_lds((gas_t)g, (las_t)l, 16, 0, 0);
}

static __device__ __forceinline__ unsigned short f2bf(float f) {
  unsigned int u = __builtin_bit_cast(unsigned int, f);
  u = u + 0x7fffu + ((u >> 16) & 1u);      // RNE
  return (unsigned short)(u >> 16);
}

// ---------- preprocessing (unchanged) ----------

__global__ void k_prep(const float* __restrict__ w, unsigned short* __restrict__ wt,
                       const unsigned char* __restrict__ pad, int* __restrict__ cnt,
                       const unsigned int* __restrict__ raw, int* __restrict__ flag) {
  if (blockIdx.x < 256) {
    int o = blockIdx.x;
    int i = threadIdx.x;
    const float* wr = w + (o * 256 + i) * 9;
    float wv[9];
    float s = 0.f;
#pragma unroll
    for (int k = 0; k < 9; ++k) { wv[k] = wr[k]; s += wv[k] * wv[k]; }
#pragma unroll
    for (int d = 32; d >= 1; d >>= 1) s += __shfl_xor(s, d);
    __shared__ float red[4];
    if ((i & 63) == 0) red[i >> 6] = s;
    __syncthreads();
    float dc = rsqrtf(red[0] + red[1] + red[2] + red[3] + 1e-8f);
#pragma unroll
    for (int k = 0; k < 9; ++k)
      wt[o * KTOT + k * 256 + i] = f2bf(wv[k] * dc);
  } else {
    int cb = blockIdx.x - 256;
    int t = cb * 256 + threadIdx.x;
    bool ip = (t < PADP) ? (pad[t] != 0) : true;
    unsigned long long m = __ballot(ip);
    int c = t >> 6;
    if ((threadIdx.x & 63) == 0 && c < NCHUNK) cnt[c] = __popcll(m);
    if (cb == 0 && threadIdx.x < 64) {
      unsigned int v = raw[threadIdx.x * 2 + 1];
      unsigned long long nz = __ballot(v != 0u);
      if (threadIdx.x == 0) flag[0] = (nz == 0ull) ? 1 : 0;
    }
  }
}

__global__ __launch_bounds__(256) void k_rankpadx(
    const float* __restrict__ x, const unsigned char* __restrict__ pad,
    const int* __restrict__ cnt, unsigned short* __restrict__ padx) {
  const int c = blockIdx.x;
  const int tid = threadIdx.x, w = tid >> 6, lane = tid & 63;
  int s = 0;
  for (int i = tid; i < c; i += 256) s += cnt[i];
#pragma unroll
  for (int d = 32; d >= 1; d >>= 1) s += __shfl_xor(s, d);
  __shared__ int red[4];
  __shared__ int rnk[64];
  if (lane == 0) red[w] = s;
  __syncthreads();
  const int S = red[0] + red[1] + red[2] + red[3];
  if (w == 0) {
    int p = c * 64 + lane;
    bool ip = (p < PADP) ? (pad[p] != 0) : true;
    unsigned long long m = __ballot(ip);
    int before = __popcll(m & ((1ull << lane) - 1ull));
    rnk[lane] = ip ? -1 : (p - (S + before));
  }
  __syncthreads();
  const int col = lane * 4;
#pragma unroll
  for (int i = 0; i < 16; ++i) {
    int rl = i * 4 + w;
    int pp = c * 64 + rl;
    if (pp >= PADP) continue;
    int rr = rnk[rl];
    ushort4 ov;
    if (rr < 0) { ov.x = 0; ov.y = 0; ov.z = 0; ov.w = 0; }
    else {
      const float4 v = *(const float4*)(x + rr * 256 + col);
      ov.x = f2bf(v.x); ov.y = f2bf(v.y); ov.z = f2bf(v.z); ov.w = f2bf(v.w);
    }
    *(ushort4*)(padx + pp * 256 + col) = ov;
  }
}

// ---------- main gathered GEMM: R16 skeleton, 4Mx4N square wave grid ----------
// BM=256 x BN=256 x BK=64, 1024 thr (16 waves 4M x 4N), wave-tile 64x64
// (4x4 frags of 16x16x32, acc 64 VGPR). Grid 196 (one block per CU, 1 round).
// LDS 160KiB exact: A ring-3 x 32KB @0/32K/64K + B dbuf 2 x 32KB @98304.
// Row-major rows of 128B, XOR slot swizzle (source side), row-contiguous
// staging (8 lanes x 16B = 128B per row per instr) -- the R18 over-fetch fix.
// idx: 9 packed-ushort VGPRs (faces t>>3 and t>>3+128), loaded ONCE pre-loop.
// Per K-tile: uniform vmcnt(2) + ONE barrier; stage B(kt+1) x2 + A(kt+2) x2;
// [8 ds_read kk0 -> 16 MFMA][8 ds_read kk1 -> 16 MFMA]. LDS frag traffic
// 256KB/tile (was 288KB): A amp 4x (was 8x).
__global__ __launch_bounds__(1024, 1) void k_main(
    const unsigned short* __restrict__ padx,   // [50001][256] bf16
    const unsigned short* __restrict__ wt,     // [256][2304] bf16
    const void* __restrict__ nbr,              // [50000][9] int64 or int32
    const int* __restrict__ flag,
    const float* __restrict__ bias,            // [256]
    float* __restrict__ out) {                 // [50000][256] f32
  __shared__ __align__(16) unsigned char sm[163840];
  const int tid = threadIdx.x;
  const int wv = tid >> 6, lane = tid & 63;
  const int m0 = blockIdx.x * BM4;
  const int q = lane & 15, hi = lane >> 4;
  const int wm = wv >> 2, wn = wv & 3;

  // bias (vmem; retired before first counted vmcnt via address-use waits)
  float bv[4];
#pragma unroll
  for (int ni = 0; ni < 4; ++ni) bv[ni] = bias[wn * 64 + ni * 16 + q];

  // packed gather indices: faces r0 = t>>3, r1 = r0+128 (9 neighbors each)
  const bool f64 = (flag[0] != 0);
  const long long* n64 = (const long long*)nbr;
  const int* n32 = (const int*)nbr;
  int f0 = m0 + (tid >> 3);       if (f0 > NF - 1) f0 = NF - 1;
  int f1 = m0 + (tid >> 3) + 128; if (f1 > NF - 1) f1 = NF - 1;
  unsigned int pk[9];
#pragma unroll
  for (int g = 0; g < 9; ++g) {
    const unsigned int a = (unsigned int)(f64 ? (int)n64[f0 * 9 + g] : n32[f0 * 9 + g]);
    const unsigned int b = (unsigned int)(f64 ? (int)n64[f1 * 9 + g] : n32[f1 * 9 + g]);
    pk[g] = a | (b << 16);
  }

  // ---- staging geometry: row-contiguous, lane-linear dest ----
  const int swsrc = ((tid & 7) ^ ((tid >> 3) & 7)) * 8;   // swizzled src slot (elems)
  const int dst16 = tid * 16;
  const unsigned short* wtb0 = wt + (tid >> 3) * KTOT + swsrc;
  const unsigned short* wtb1 = wt + (128 + (tid >> 3)) * KTOT + swsrc;

  // ---- fragment read offsets ----
  const int q7 = q & 7;
  const int s0 = ((hi    ) ^ q7) * 16;   // kk=0 slot (bytes)
  const int s1 = ((4 + hi) ^ q7) * 16;   // kk=1 slot
  int aof[4], bof[4];
#pragma unroll
  for (int mi = 0; mi < 4; ++mi) aof[mi] = (wm * 64 + mi * 16 + q) * 128;
#pragma unroll
  for (int ni = 0; ni < 4; ++ni) bof[ni] = (wn * 64 + ni * 16 + q) * 128;

  f32x4 acc[4][4];
#pragma unroll
  for (int a = 0; a < 4; ++a)
#pragma unroll
    for (int b = 0; b < 4; ++b) {
      acc[a][b][0] = 0.f; acc[a][b][1] = 0.f; acc[a][b][2] = 0.f; acc[a][b][3] = 0.f;
    }

  // ---- prologue (queue order: A(0) x2, B(0) x2, A(1) x2) ----
  {
    const unsigned int pa = pk[0];
    gll16(padx + (pa & 0xffffu) * 256 + swsrc, sm + dst16);
    gll16(padx + (pa >> 16)     * 256 + swsrc, sm + 16384 + dst16);
    gll16(wtb0, sm + BB + dst16);
    gll16(wtb1, sm + BB + 16384 + dst16);
    gll16(padx + (pa & 0xffffu) * 256 + 64 + swsrc, sm + 32768 + dst16);
    gll16(padx + (pa >> 16)     * 256 + 64 + swsrc, sm + 32768 + 16384 + dst16);
  }

#define LD(p) (*(const bf16x8*)(p))
#define SB __builtin_amdgcn_sched_barrier(0);
#define MF16(A0,A1,A2,A3,B0,B1,B2,B3) \
  acc[0][0]=__builtin_amdgcn_mfma_f32_16x16x32_bf16(A0,B0,acc[0][0],0,0,0); \
  acc[0][1]=__builtin_amdgcn_mfma_f32_16x16x32_bf16(A0,B1,acc[0][1],0,0,0); \
  acc[0][2]=__builtin_amdgcn_mfma_f32_16x16x32_bf16(A0,B2,acc[0][2],0,0,0); \
  acc[0][3]=__builtin_amdgcn_mfma_f32_16x16x32_bf16(A0,B3,acc[0][3],0,0,0); \
  acc[1][0]=__builtin_amdgcn_mfma_f32_16x16x32_bf16(A1,B0,acc[1][0],0,0,0); \
  acc[1][1]=__builtin_amdgcn_mfma_f32_16x16x32_bf16(A1,B1,acc[1][1],0,0,0); \
  acc[1][2]=__builtin_amdgcn_mfma_f32_16x16x32_bf16(A1,B2,acc[1][2],0,0,0); \
  acc[1][3]=__builtin_amdgcn_mfma_f32_16x16x32_bf16(A1,B3,acc[1][3],0,0,0); \
  acc[2][0]=__builtin_amdgcn_mfma_f32_16x16x32_bf16(A2,B0,acc[2][0],0,0,0); \
  acc[2][1]=__builtin_amdgcn_mfma_f32_16x16x32_bf16(A2,B1,acc[2][1],0,0,0); \
  acc[2][2]=__builtin_amdgcn_mfma_f32_16x16x32_bf16(A2,B2,acc[2][2],0,0,0); \
  acc[2][3]=__builtin_amdgcn_mfma_f32_16x16x32_bf16(A2,B3,acc[2][3],0,0,0); \
  acc[3][0]=__builtin_amdgcn_mfma_f32_16x16x32_bf16(A3,B0,acc[3][0],0,0,0); \
  acc[3][1]=__builtin_amdgcn_mfma_f32_16x16x32_bf16(A3,B1,acc[3][1],0,0,0); \
  acc[3][2]=__builtin_amdgcn_mfma_f32_16x16x32_bf16(A3,B2,acc[3][2],0,0,0); \
  acc[3][3]=__builtin_amdgcn_mfma_f32_16x16x32_bf16(A3,B3,acc[3][3],0,0,0);

#define KTILE(kt) { \
  asm volatile("s_waitcnt vmcnt(2)" ::: "memory"); \
  SB __builtin_amdgcn_s_barrier(); SB \
  { const int ub = ((kt)+1 < NKT) ? (kt)+1 : NKT-1; \
    const int bO_ = BB + ((((kt)+1) & 1) << 15); \
    gll16(wtb0 + ub*64, sm + bO_ + dst16); \
    gll16(wtb1 + ub*64, sm + bO_ + 16384 + dst16); } \
  { const int ua = ((kt)+2 < NKT) ? (kt)+2 : NKT-1; \
    const int aS_ = (ua % 3) * 32768; \
    const int c0 = (ua & 3) * 64; \
    const unsigned int pa = pk[ua >> 2]; \
    gll16(padx + (pa & 0xffffu)*256 + c0 + swsrc, sm + aS_ + dst16); \
    gll16(padx + (pa >> 16)    *256 + c0 + swsrc, sm + aS_ + 16384 + dst16); } \
  SB \
  { const int aC_ = ((kt) % 3) * 32768; \
    const int bC_ = BB + (((kt) & 1) << 15); \
    bf16x8 a0 = LD(sm + aC_ + aof[0] + s0), a1 = LD(sm + aC_ + aof[1] + s0); \
    bf16x8 a2 = LD(sm + aC_ + aof[2] + s0), a3 = LD(sm + aC_ + aof[3] + s0); \
    bf16x8 b0 = LD(sm + bC_ + bof[0] + s0), b1 = LD(sm + bC_ + bof[1] + s0); \
    bf16x8 b2 = LD(sm + bC_ + bof[2] + s0), b3 = LD(sm + bC_ + bof[3] + s0); \
    __builtin_amdgcn_s_setprio(1); \
    MF16(a0,a1,a2,a3,b0,b1,b2,b3) \
    __builtin_amdgcn_s_setprio(0); \
    a0 = LD(sm + aC_ + aof[0] + s1); a1 = LD(sm + aC_ + aof[1] + s1); \
    a2 = LD(sm + aC_ + aof[2] + s1); a3 = LD(sm + aC_ + aof[3] + s1); \
    b0 = LD(sm + bC_ + bof[0] + s1); b1 = LD(sm + bC_ + bof[1] + s1); \
    b2 = LD(sm + bC_ + bof[2] + s1); b3 = LD(sm + bC_ + bof[3] + s1); \
    __builtin_amdgcn_s_setprio(1); \
    MF16(a0,a1,a2,a3,b0,b1,b2,b3) \
    __builtin_amdgcn_s_setprio(0); } \
  SB \
}

  KTILE(0)  KTILE(1)  KTILE(2)  KTILE(3)  KTILE(4)  KTILE(5)
  KTILE(6)  KTILE(7)  KTILE(8)  KTILE(9)  KTILE(10) KTILE(11)
  KTILE(12) KTILE(13) KTILE(14) KTILE(15) KTILE(16) KTILE(17)
  KTILE(18) KTILE(19) KTILE(20) KTILE(21) KTILE(22) KTILE(23)
  KTILE(24) KTILE(25) KTILE(26) KTILE(27) KTILE(28) KTILE(29)
  KTILE(30) KTILE(31) KTILE(32) KTILE(33) KTILE(34) KTILE(35)
#undef KTILE
#undef MF16
#undef LD
#undef SB
  asm volatile("s_waitcnt vmcnt(0)" ::: "memory");

  // ---- epilogue: bias + store (D: col = q, row = hi*4 + rr) ----
#pragma unroll
  for (int ni = 0; ni < 4; ++ni) {
    const int col = wn * 64 + ni * 16 + q;
#pragma unroll
    for (int mi = 0; mi < 4; ++mi) {
#pragma unroll
      for (int rr = 0; rr < 4; ++rr) {
        const int row = m0 + wm * 64 + mi * 16 + hi * 4 + rr;
        if (row < NF) out[row * 256 + col] = acc[mi][ni][rr] + bv[ni];
      }
    }
  }
}

extern "C" void kernel_launch(void* const* d_in, const int* in_sizes, int n_in,
                              void* d_out, int out_size, void* d_ws, size_t ws_size,
                              hipStream_t stream) {
  const float* x = (const float*)d_in[0];
  const float* wfull = (const float*)d_in[1];
  const float* bias = (const float*)d_in[2];
  const void* nbr = d_in[3];
  const unsigned char* pad = (const unsigned char*)d_in[4];
  float* out = (float*)d_out;
  char* ws = (char*)d_ws;

  unsigned short* wt   = (unsigned short*)(ws + WT_OFF);
  int* flag            = (int*)(ws + FLAG_OFF);
  int* cnt             = (int*)(ws + CNT_OFF);
  unsigned short* padx = (unsigned short*)(ws + PADX_OFF);

  k_prep<<<452, 256, 0, stream>>>(wfull, wt, pad, cnt, (const unsigned int*)nbr, flag);
  k_rankpadx<<<NCHUNK, 256, 0, stream>>>(x, pad, cnt, padx);
  k_main<<<NBLK4, 1024, 0, stream>>>(padx, wt, nbr, flag, bias, out);
}

// Round 20
// 81.966 us; speedup vs baseline: 10.6489x; 1.3742x over previous
//
#include <hip/hip_runtime.h>

#define NF    50000
#define PADP  50001
#define KN    9
#define KTOT  2304
#define NCHUNK 782
#define BM3   224
#define NBLK3 224        // single round on 256 CUs
#define NKT   36         // 2304/64 K-tiles
#define ABUF  28672      // one A buffer: 224 rows x 128B
#define BB    86016      // B dbuf base (2 x 32768)
#define IDXO  151552     // ushort idx cache 224*9*2 = 4032 -> total 155584

// ---- ws layout (bytes) ----
#define WT_OFF   0u
#define FLAG_OFF 1179648u
#define PADX_OFF 1183744u

typedef float f32x4 __attribute__((ext_vector_type(4)));
typedef __bf16 bf16x8 __attribute__((ext_vector_type(8)));

typedef const __attribute__((address_space(1))) unsigned int* gas_t;
typedef __attribute__((address_space(3))) unsigned int* las_t;

static __device__ __forceinline__ void gll16(const void* g, void* l) {
  __builtin_amdgcn_global_load_lds((gas_t)g, (las_t)l, 16, 0, 0);
}

static __device__ __forceinline__ unsigned short f2bf(float f) {
  unsigned int u = __builtin_bit_cast(unsigned int, f);
  u = u + 0x7fffu + ((u >> 16) & 1u);      // RNE
  return (unsigned short)(u >> 16);
}

// ---------- fused preprocessing: ONE kernel, two block roles ----------
// blocks 0..255: weight demod + transpose (block 0 also: int64-vs-int32 flag)
// blocks 256..1037 (c = b-256): self-computed pad-prefix (scan pad[0..c*64)),
//   ballot ranks for chunk c, fp32->bf16 conversion of 64 padded_x rows.
__global__ __launch_bounds__(256) void k_prep2(
    const float* __restrict__ w, unsigned short* __restrict__ wt,
    const unsigned char* __restrict__ pad,
    const unsigned int* __restrict__ raw, int* __restrict__ flag,
    const float* __restrict__ x, unsigned short* __restrict__ padx) {
  const int tid = threadIdx.x, wl = tid >> 6, lane = tid & 63;
  if (blockIdx.x < 256) {
    int o = blockIdx.x;
    const float* wr = w + (o * 256 + tid) * 9;
    float wv[9];
    float s = 0.f;
#pragma unroll
    for (int k = 0; k < 9; ++k) { wv[k] = wr[k]; s += wv[k] * wv[k]; }
#pragma unroll
    for (int d = 32; d >= 1; d >>= 1) s += __shfl_xor(s, d);
    __shared__ float red[4];
    if (lane == 0) red[wl] = s;
    __syncthreads();
    float dc = rsqrtf(red[0] + red[1] + red[2] + red[3] + 1e-8f);
#pragma unroll
    for (int k = 0; k < 9; ++k)
      wt[o * KTOT + k * 256 + tid] = f2bf(wv[k] * dc);
    if (o == 0 && tid < 64) {
      unsigned int v = raw[tid * 2 + 1];
      unsigned long long nz = __ballot(v != 0u);
      if (tid == 0) flag[0] = (nz == 0ull) ? 1 : 0;
    }
    return;
  }
  // ---- rank + padx role ----
  const int c = blockIdx.x - 256;
  // self-computed prefix: pads in chunks [0, c) = sum of pad[0 .. c*64)
  int s = 0;
  {
    const uint4* p4 = (const uint4*)pad;
    const int n16 = c * 4;                  // c*64 bytes / 16
    for (int j = tid; j < n16; j += 256) {
      uint4 v = p4[j];
#pragma unroll
      for (int wdi = 0; wdi < 4; ++wdi) {
        unsigned int u = (&v.x)[wdi];
        s += (int)((u & 0xffu) + ((u >> 8) & 0xffu) + ((u >> 16) & 0xffu) + (u >> 24));
      }
    }
  }
#pragma unroll
  for (int d = 32; d >= 1; d >>= 1) s += __shfl_xor(s, d);
  __shared__ int red[4];
  __shared__ int rnk[64];
  if (lane == 0) red[wl] = s;
  __syncthreads();
  const int S = red[0] + red[1] + red[2] + red[3];
  if (wl == 0) {
    int p = c * 64 + lane;
    bool ip = (p < PADP) ? (pad[p] != 0) : true;
    unsigned long long m = __ballot(ip);
    int before = __popcll(m & ((1ull << lane) - 1ull));
    rnk[lane] = ip ? -1 : (p - (S + before));
  }
  __syncthreads();
  const int col = lane * 4;
#pragma unroll
  for (int i = 0; i < 16; ++i) {
    int rl = i * 4 + wl;
    int pp = c * 64 + rl;
    if (pp >= PADP) continue;
    int rr = rnk[rl];
    ushort4 ov;
    if (rr < 0) { ov.x = 0; ov.y = 0; ov.z = 0; ov.w = 0; }
    else {
      const float4 v = *(const float4*)(x + rr * 256 + col);
      ov.x = f2bf(v.x); ov.y = f2bf(v.y); ov.z = f2bf(v.z); ov.w = f2bf(v.w);
    }
    *(ushort4*)(padx + pp * 256 + col) = ov;
  }
}

// ---------- main gathered GEMM: R17 verbatim (best measured: 67.5us) ----------
// BM=224 x BN=256 x BK=64, 1024 thr (16 waves, 2M x 8N), wave-tile 112x32.
// LDS: A ring-3 x 28KB + B dbuf 2 x 32KB + ushort idx 4KB = 152KB. Grid 224.
// Per K-tile (ONE barrier), 2-color wave stagger (even: kk0->kk1, odd: kk1->kk0).
__global__ __launch_bounds__(1024, 1) void k_main(
    const unsigned short* __restrict__ padx,   // [50001][256] bf16
    const unsigned short* __restrict__ wt,     // [256][2304] bf16
    const void* __restrict__ nbr,              // [50000][9] int64 or int32
    const int* __restrict__ flag,
    const float* __restrict__ bias,            // [256]
    float* __restrict__ out) {                 // [50000][256] f32
  __shared__ __align__(16) unsigned char sm[155584];
  const int tid = threadIdx.x;
  const int wv = tid >> 6, lane = tid & 63;
  const int m0 = blockIdx.x * BM3;
  unsigned short* idxl = (unsigned short*)(sm + IDXO);

  const int q = lane & 15, hi = lane >> 4;
  const int wm = wv >> 3, wn = wv & 7;

  float bv[2];
#pragma unroll
  for (int ni = 0; ni < 2; ++ni) bv[ni] = bias[wn * 32 + ni * 16 + q];

  // ushort idx cache: 224 rows x 9 neighbors (clamped faces; values < 50001)
  const bool f64 = (flag[0] != 0);
  const long long* n64 = (const long long*)nbr;
  const int* n32 = (const int*)nbr;
  for (int e = tid; e < BM3 * 9; e += 1024) {
    int f = m0 + e / 9;
    if (f >= NF) f = NF - 1;
    int k = e - (e / 9) * 9;
    idxl[e] = (unsigned short)(f64 ? (int)n64[f * KN + k] : n32[f * KN + k]);
  }
  __syncthreads();   // drains bias/idx vmem -> clean queue

  // ---- staging geometry ----
  const int swsrc = ((tid & 7) ^ ((tid >> 3) & 7)) * 8;
  const int dst16 = tid * 16;
  const int r0 = tid >> 3;                 // A rows (w0-13): r0 (0..111), r0+112
  const unsigned short* wtb0 = wt + (tid >> 3) * KTOT + swsrc;          // B rows 0..127
  const unsigned short* wtb1 = wt + (128 + (tid >> 3)) * KTOT + swsrc;  // 128..255

  // ---- fragment read offsets; parity picks kk order ----
  const int q7 = q & 7;
  const int sl0 = ((hi    ) ^ q7) * 16;    // kk=0 slot
  const int sl1 = ((4 + hi) ^ q7) * 16;    // kk=1 slot
  const int par = wv & 1;
  const int sA = par ? sl1 : sl0;          // first-processed kk slot
  const int sB = par ? sl0 : sl1;          // second-processed kk slot
  int aoffb[7], bofb[2];
#pragma unroll
  for (int mi = 0; mi < 7; ++mi) aoffb[mi] = (wm * 112 + mi * 16 + q) * 128;
#pragma unroll
  for (int ni = 0; ni < 2; ++ni) bofb[ni] = (wn * 32 + ni * 16 + q) * 128;

  f32x4 acc[7][2];
#pragma unroll
  for (int a = 0; a < 7; ++a)
#pragma unroll
    for (int b = 0; b < 2; ++b) {
      acc[a][b][0] = 0.f; acc[a][b][1] = 0.f; acc[a][b][2] = 0.f; acc[a][b][3] = 0.f;
    }

  int pc0 = 0, pc1 = 0, pn0 = 0, pn1 = 0;
  if (wv < 14) {
    pc0 = idxl[r0 * 9]; pc1 = idxl[(r0 + 112) * 9];
    pn0 = pc0; pn1 = pc1;
  }

  // ---- prologue (queue order: A(0), B(0), A(1)) ----
  if (wv < 14) {
    gll16(padx + pc0 * 256 +  0 + swsrc, sm + dst16);
    gll16(padx + pc1 * 256 +  0 + swsrc, sm + 14336 + dst16);
  }
  gll16(wtb0, sm + BB + dst16);
  gll16(wtb1, sm + BB + 16384 + dst16);
  if (wv < 14) {
    gll16(padx + pc0 * 256 + 64 + swsrc, sm + ABUF + dst16);
    gll16(padx + pc1 * 256 + 64 + swsrc, sm + ABUF + 14336 + dst16);
  }

  bf16x8 af[7], bq[2], af2[7], bq2[2];
  int aC = 0, aN = ABUF, aS = 2 * ABUF;
  int bC = BB, bO = BB + 32768;

#define LD(p) (*(const bf16x8*)(p))
#define SB __builtin_amdgcn_sched_barrier(0);
#define MFA(MI) \
  acc[MI][0] = __builtin_amdgcn_mfma_f32_16x16x32_bf16(af[MI], bq[0], acc[MI][0], 0,0,0); \
  acc[MI][1] = __builtin_amdgcn_mfma_f32_16x16x32_bf16(af[MI], bq[1], acc[MI][1], 0,0,0);
#define MFB(MI) \
  acc[MI][0] = __builtin_amdgcn_mfma_f32_16x16x32_bf16(af2[MI], bq2[0], acc[MI][0], 0,0,0); \
  acc[MI][1] = __builtin_amdgcn_mfma_f32_16x16x32_bf16(af2[MI], bq2[1], acc[MI][1], 0,0,0);

#pragma unroll 1
  for (int kt = 0; kt < NKT; ++kt) {
    // ---- top: residency + the ONLY barrier ----
    if (wv < 14) asm volatile("s_waitcnt vmcnt(2)" ::: "memory");
    else         asm volatile("s_waitcnt vmcnt(0)" ::: "memory");
    SB
    __builtin_amdgcn_s_barrier();
    SB
    // ---- stages: B(kt+1)->bO (all), then A(kt+2)->aS (w0-13) ----
    {
      const int kb = ((kt + 1 < NKT) ? kt + 1 : NKT - 1) * 64;
      gll16(wtb0 + kb, sm + bO + dst16);
      gll16(wtb1 + kb, sm + bO + 16384 + dst16);
    }
    SB
    if (wv < 14) {
      const int c0 = ((kt + 2) & 3) * 64;
      const int u0 = ((kt & 3) < 2) ? pc0 : pn0;
      const int u1 = ((kt & 3) < 2) ? pc1 : pn1;
      gll16(padx + u0 * 256 + c0 + swsrc, sm + aS + dst16);
      gll16(padx + u1 * 256 + c0 + swsrc, sm + aS + 14336 + dst16);
    }
    if ((kt & 3) == 1 && wv < 14) {
      int gn = (kt >> 2) + 1; if (gn > 8) gn = 8;
      pn0 = idxl[r0 * 9 + gn]; pn1 = idxl[(r0 + 112) * 9 + gn];
    }
    SB
    // ---- first kk (parity-selected): 9 ds_reads + 14 MFMA ----
#pragma unroll
    for (int mi = 0; mi < 7; ++mi) af[mi] = LD(sm + aC + aoffb[mi] + sA);
    bq[0] = LD(sm + bC + bofb[0] + sA);
    bq[1] = LD(sm + bC + bofb[1] + sA);
    __builtin_amdgcn_s_setprio(1);
    MFA(0) MFA(1) MFA(2) MFA(3) MFA(4) MFA(5) MFA(6)
    __builtin_amdgcn_s_setprio(0);
    // ---- second kk: 9 ds_reads + 14 MFMA (separate regs: no WAR stall) ----
#pragma unroll
    for (int mi = 0; mi < 7; ++mi) af2[mi] = LD(sm + aC + aoffb[mi] + sB);
    bq2[0] = LD(sm + bC + bofb[0] + sB);
    bq2[1] = LD(sm + bC + bofb[1] + sB);
    __builtin_amdgcn_s_setprio(1);
    MFB(0) MFB(1) MFB(2) MFB(3) MFB(4) MFB(5) MFB(6)
    __builtin_amdgcn_s_setprio(0);
    SB
    // ---- rotations ----
    { int t0 = aC; aC = aN; aN = aS; aS = t0; }
    { int t1 = bC; bC = bO; bO = t1; }
    if ((kt & 3) == 3) { pc0 = pn0; pc1 = pn1; }
  }
#undef MFA
#undef MFB
#undef LD
#undef SB
  asm volatile("s_waitcnt vmcnt(0)" ::: "memory");

  // ---- epilogue: bias + store (D: col = q, row = hi*4 + rr) ----
#pragma unroll
  for (int ni = 0; ni < 2; ++ni) {
    const int col = wn * 32 + ni * 16 + q;
#pragma unroll
    for (int mi = 0; mi < 7; ++mi) {
#pragma unroll
      for (int rr = 0; rr < 4; ++rr) {
        const int row = m0 + wm * 112 + mi * 16 + hi * 4 + rr;
        if (row < NF) out[row * 256 + col] = acc[mi][ni][rr] + bv[ni];
      }
    }
  }
}

extern "C" void kernel_launch(void* const* d_in, const int* in_sizes, int n_in,
                              void* d_out, int out_size, void* d_ws, size_t ws_size,
                              hipStream_t stream) {
  const float* x = (const float*)d_in[0];
  const float* wfull = (const float*)d_in[1];
  const float* bias = (const float*)d_in[2];
  const void* nbr = d_in[3];
  const unsigned char* pad = (const unsigned char*)d_in[4];
  float* out = (float*)d_out;
  char* ws = (char*)d_ws;

  unsigned short* wt   = (unsigned short*)(ws + WT_OFF);
  int* flag            = (int*)(ws + FLAG_OFF);
  unsigned short* padx = (unsigned short*)(ws + PADX_OFF);

  k_prep2<<<256 + NCHUNK, 256, 0, stream>>>(wfull, wt, pad,
                                            (const unsigned int*)nbr, flag, x, padx);
  k_main<<<NBLK3, 1024, 0, stream>>>(padx, wt, nbr, flag, bias, out);
}